// Round 17
// baseline (133.530 us; speedup 1.0000x reference)
//
#include <hip/hip_runtime.h>
#include <cstdint>
#include <cstddef>

#define DEV __device__ __forceinline__

typedef __bf16 bf16x8 __attribute__((ext_vector_type(8)));
typedef float f32x4 __attribute__((ext_vector_type(4)));
typedef unsigned short us8 __attribute__((ext_vector_type(8)));
typedef unsigned short us4 __attribute__((ext_vector_type(4)));

typedef const __attribute__((address_space(1))) unsigned int GUI;
typedef __attribute__((address_space(3))) unsigned int LUI;

DEV unsigned short f2bf(float f) {
  unsigned int u = __builtin_bit_cast(unsigned int, f);
  u += 0x7fffu + ((u >> 16) & 1u);
  return (unsigned short)(u >> 16);
}
DEV float bf2f(unsigned short h) {
  unsigned int u = ((unsigned int)h) << 16;
  return __builtin_bit_cast(float, u);
}

// exact-GELU via A&S 7.1.26 erf approximation (|erf err| <= 1.5e-7)
DEV float gelu_exact(float x) {
  float xs = x * 0.70710678118654752f;
  float a = fabsf(xs);
  float t = __builtin_amdgcn_rcpf(fmaf(0.3275911f, a, 1.0f));
  float poly = t * fmaf(t, fmaf(t, fmaf(t, fmaf(t, 1.061405429f, -1.453152027f),
                                        1.421413741f), -0.284496736f), 0.254829592f);
  float erfa = 1.0f - poly * __expf(-a * a);
  float er = (xs < 0.f) ? -erfa : erfa;
  return 0.5f * x * (1.0f + er);
}

// ---------- fused prep: z->bf16, weight transposes, bias concat ----------
DEV void tr32(const float* __restrict__ in, unsigned short* __restrict__ out,
              int K, int N, int k0, int n0) {
  __shared__ float tile[32][33];
  const int tx = threadIdx.x & 31, ty = threadIdx.x >> 5;  // 256 thr = 32x8
#pragma unroll
  for (int i = 0; i < 32; i += 8)
    tile[ty + i][tx] = in[(size_t)(k0 + ty + i) * N + n0 + tx];
  __syncthreads();
#pragma unroll
  for (int i = 0; i < 32; i += 8)
    out[(size_t)(n0 + ty + i) * K + k0 + tx] = f2bf(tile[tx][ty + i]);
}

__global__ __launch_bounds__(256) void k_prep(
    const float* __restrict__ z, unsigned short* __restrict__ zb,
    const float* __restrict__ Wq, const float* __restrict__ Wk,
    const float* __restrict__ Wv, const float* __restrict__ Wo,
    unsigned short* __restrict__ Wsq,
    const float* __restrict__ W1, unsigned short* __restrict__ W1T,
    const float* __restrict__ W2, unsigned short* __restrict__ W2T,
    const float* __restrict__ bq, const float* __restrict__ bk,
    const float* __restrict__ bv, float* __restrict__ biasqkv) {
  const int j = blockIdx.x;
  const int tid = threadIdx.x;
  if (j < 4096) {
    int i = j * 256 + tid;
    float4 v = ((const float4*)z)[i];
    us4 o;
    o.x = f2bf(v.x); o.y = f2bf(v.y); o.z = f2bf(v.z); o.w = f2bf(v.w);
    *(us4*)(zb + (size_t)i * 4) = o;
  } else if (j < 5120) {
    int t = j - 4096;
    int mat = t >> 8, tile = t & 255;
    const float* in = mat == 0 ? Wq : mat == 1 ? Wk : mat == 2 ? Wv : Wo;
    tr32(in, Wsq + (size_t)mat * 262144, 512, 512, (tile >> 4) * 32, (tile & 15) * 32);
  } else if (j < 6144) {
    int t = j - 5120;
    tr32(W1, W1T, 512, 2048, (t / 64) * 32, (t % 64) * 32);
  } else if (j < 7168) {
    int t = j - 6144;
    tr32(W2, W2T, 2048, 512, (t / 16) * 32, (t % 16) * 32);
  } else {
    for (int i = tid; i < 1536; i += 256)
      biasqkv[i] = (i < 512) ? bq[i] : (i < 1024 ? bk[i - 512] : bv[i - 1024]);
  }
}

// ========== GEMM body A: 256x256 tile, BK=64, 8 waves (round-8 best) ======
template <int MODE>
DEV void gemm256_body(const unsigned short* __restrict__ A,
                      const unsigned short* __restrict__ BT,
                      const float* __restrict__ bias,
                      unsigned short* __restrict__ outp,
                      int K, int N) {
  __shared__ __align__(16) unsigned short As[2 * 16384];
  __shared__ __align__(16) unsigned short Bs[2 * 16384];
  const int tid = threadIdx.x;
  const int wave = tid >> 6, lane = tid & 63;
  const int wm = wave >> 2, wn = wave & 3;

  const int nx = gridDim.x, ny = gridDim.y;
  const int nwg = nx * ny;
  const int lid = blockIdx.y * nx + blockIdx.x;
  const int q8 = nwg >> 3, r8 = nwg & 7;
  const int xcd = lid & 7, slot = lid >> 3;
  const int wid = (xcd < r8 ? xcd * (q8 + 1) : r8 * (q8 + 1) + (xcd - r8) * q8) + slot;
  const int bx  = wid % nx;   // fastest: B-panel
  const int by  = wid / nx;   // slowest: A-panel

  const int rbase = by * 256;
  const int nbase = bx * 256;
  const int nkt = K >> 6;

  float bv_[4];
#pragma unroll
  for (int n = 0; n < 4; ++n)
    bv_[n] = bias[nbase + wn * 64 + n * 16 + (lane & 15)];
  asm volatile("s_waitcnt vmcnt(0)" ::: "memory");

  auto STAGE = [&](int buf, int k0) {
#pragma unroll
    for (int t = 0; t < 4; ++t) {
      int s = t * 512 + tid;
      int row = s >> 3;
      int col = ((s & 7) ^ (row & 7)) << 3;
      const unsigned short* ga = A + (size_t)(rbase + row) * K + k0 + col;
      const unsigned short* gb = BT + (size_t)(nbase + row) * K + k0 + col;
      const int dst = buf * 16384 + (t * 512 + wave * 64) * 8;
      __builtin_amdgcn_global_load_lds((GUI*)ga, (LUI*)(As + dst), 16, 0, 0);
      __builtin_amdgcn_global_load_lds((GUI*)gb, (LUI*)(Bs + dst), 16, 0, 0);
    }
  };

  f32x4 acc[8][4] = {};
  STAGE(0, 0);

  for (int kt = 0; kt < nkt; ++kt) {
    const int cur = kt & 1;
    if (kt + 1 < nkt) {
      STAGE(cur ^ 1, (kt + 1) * 64);
      asm volatile("s_waitcnt vmcnt(8)" ::: "memory");
    } else {
      asm volatile("s_waitcnt vmcnt(0)" ::: "memory");
    }
    __builtin_amdgcn_s_barrier();

#pragma unroll
    for (int ks = 0; ks < 2; ++ks) {
      bf16x8 af[8], bfr[4];
#pragma unroll
      for (int m = 0; m < 8; ++m) {
        int row = wm * 128 + m * 16 + (lane & 15);
        int ch = (ks * 4 + (lane >> 4)) ^ (row & 7);
        af[m] = __builtin_bit_cast(bf16x8, *(const us8*)(As + cur * 16384 + row * 64 + ch * 8));
      }
#pragma unroll
      for (int n = 0; n < 4; ++n) {
        int row = wn * 64 + n * 16 + (lane & 15);
        int ch = (ks * 4 + (lane >> 4)) ^ (row & 7);
        bfr[n] = __builtin_bit_cast(bf16x8, *(const us8*)(Bs + cur * 16384 + row * 64 + ch * 8));
      }
      __builtin_amdgcn_s_setprio(1);
#pragma unroll
      for (int m = 0; m < 8; ++m)
#pragma unroll
        for (int n = 0; n < 4; ++n)
          acc[m][n] = __builtin_amdgcn_mfma_f32_16x16x32_bf16(af[m], bfr[n], acc[m][n], 0, 0, 0);
      __builtin_amdgcn_s_setprio(0);
    }
    asm volatile("s_waitcnt lgkmcnt(0)" ::: "memory");
    __builtin_amdgcn_s_barrier();
  }

#pragma unroll
  for (int m = 0; m < 8; ++m) {
    int grow0 = rbase + wm * 128 + m * 16 + ((lane >> 4) << 2);
#pragma unroll
    for (int n = 0; n < 4; ++n) {
      int gcol = nbase + wn * 64 + n * 16 + (lane & 15);
#pragma unroll
      for (int r = 0; r < 4; ++r) {
        float v = acc[m][n][r] + bv_[n];
        if (MODE == 2) v = gelu_exact(v);
        outp[(size_t)(grow0 + r) * N + gcol] = f2bf(v);
      }
    }
  }
}

// ========== GEMM body B: 128x128 tile, BK=64, 4 waves (round-12 proven) ====
template <int MODE>
DEV void gemm128_body(const unsigned short* __restrict__ A,
                      const unsigned short* __restrict__ BT,
                      const float* __restrict__ bias,
                      unsigned short* __restrict__ outp,
                      int K, int N) {
  __shared__ __align__(16) unsigned short As[2 * 8192];
  __shared__ __align__(16) unsigned short Bs[2 * 8192];
  const int tid = threadIdx.x;
  const int wave = tid >> 6, lane = tid & 63;
  const int wm = wave >> 1, wn = wave & 1;
  const int q = lane >> 4, l15 = lane & 15;

  const int nx = gridDim.x, ny = gridDim.y;
  const int nwg = nx * ny;
  const int lid = blockIdx.y * nx + blockIdx.x;
  const int q8 = nwg >> 3, r8 = nwg & 7;
  const int xcd = lid & 7, slot = lid >> 3;
  const int wid = (xcd < r8 ? xcd * (q8 + 1) : r8 * (q8 + 1) + (xcd - r8) * q8) + slot;
  const int bx = wid % nx;   // fastest: B-panel
  const int by = wid / nx;   // slowest: A-panel

  const int rbase = by * 128;
  const int nbase = bx * 128;
  const int nkt = K >> 6;

  float bv_[4];
#pragma unroll
  for (int n = 0; n < 4; ++n) bv_[n] = bias[nbase + wn * 64 + n * 16 + l15];
  asm volatile("s_waitcnt vmcnt(0)" ::: "memory");

  auto STAGE = [&](int buf, int k0) {
#pragma unroll
    for (int t = 0; t < 4; ++t) {
      int s = t * 256 + tid;
      int row = s >> 3;
      int col = ((s & 7) ^ (row & 7)) << 3;
      const unsigned short* ga = A + (size_t)(rbase + row) * K + k0 + col;
      const unsigned short* gb = BT + (size_t)(nbase + row) * K + k0 + col;
      const int dst = buf * 8192 + (t * 256 + wave * 64) * 8;
      __builtin_amdgcn_global_load_lds((GUI*)ga, (LUI*)(As + dst), 16, 0, 0);
      __builtin_amdgcn_global_load_lds((GUI*)gb, (LUI*)(Bs + dst), 16, 0, 0);
    }
  };

  f32x4 acc[4][4] = {};
  STAGE(0, 0);

  for (int kt = 0; kt < nkt; ++kt) {
    const int cur = kt & 1;
    if (kt + 1 < nkt) {
      STAGE(cur ^ 1, (kt + 1) * 64);
      asm volatile("s_waitcnt vmcnt(8)" ::: "memory");
    } else {
      asm volatile("s_waitcnt vmcnt(0)" ::: "memory");
    }
    __builtin_amdgcn_s_barrier();

#pragma unroll
    for (int ks = 0; ks < 2; ++ks) {
      bf16x8 af[4], bfr[4];
#pragma unroll
      for (int m = 0; m < 4; ++m) {
        int row = wm * 64 + m * 16 + l15;
        int ch = (ks * 4 + q) ^ (row & 7);
        af[m] = __builtin_bit_cast(bf16x8, *(const us8*)(As + cur * 8192 + row * 64 + ch * 8));
      }
#pragma unroll
      for (int n = 0; n < 4; ++n) {
        int row = wn * 64 + n * 16 + l15;
        int ch = (ks * 4 + q) ^ (row & 7);
        bfr[n] = __builtin_bit_cast(bf16x8, *(const us8*)(Bs + cur * 8192 + row * 64 + ch * 8));
      }
      __builtin_amdgcn_s_setprio(1);
#pragma unroll
      for (int m = 0; m < 4; ++m)
#pragma unroll
        for (int n = 0; n < 4; ++n)
          acc[m][n] = __builtin_amdgcn_mfma_f32_16x16x32_bf16(af[m], bfr[n], acc[m][n], 0, 0, 0);
      __builtin_amdgcn_s_setprio(0);
    }
    asm volatile("s_waitcnt lgkmcnt(0)" ::: "memory");
    __builtin_amdgcn_s_barrier();
  }

#pragma unroll
  for (int m = 0; m < 4; ++m) {
    int grow0 = rbase + wm * 64 + m * 16 + (q << 2);
#pragma unroll
    for (int n = 0; n < 4; ++n) {
      int gcol = nbase + wn * 64 + n * 16 + l15;
#pragma unroll
      for (int r = 0; r < 4; ++r) {
        float v = acc[m][n][r] + bv_[n];
        if (MODE == 2) v = gelu_exact(v);
        outp[(size_t)(grow0 + r) * N + gcol] = f2bf(v);
      }
    }
  }
}

__global__ __launch_bounds__(512) void k_qkv(const unsigned short* __restrict__ A,
                                             const unsigned short* __restrict__ BT,
                                             const float* __restrict__ bias,
                                             unsigned short* __restrict__ outp, int K, int N) {
  gemm256_body<0>(A, BT, bias, outp, K, N);
}
__global__ __launch_bounds__(512) void k_ffn1(const unsigned short* __restrict__ A,
                                              const unsigned short* __restrict__ BT,
                                              const float* __restrict__ bias,
                                              unsigned short* __restrict__ outp, int K, int N) {
  gemm256_body<2>(A, BT, bias, outp, K, N);
}
__global__ __launch_bounds__(256) void k_ffn2(const unsigned short* __restrict__ A,
                                              const unsigned short* __restrict__ BT,
                                              const float* __restrict__ bias,
                                              unsigned short* __restrict__ outp, int K, int N) {
  gemm128_body<0>(A, BT, bias, outp, K, N);
}

// ===== fused attention + Wo projection + LN1: z1b = LN(zb + attn@Wo + bo) =====
__global__ __launch_bounds__(512) void k_awl(
    const unsigned short* __restrict__ qkv,
    const unsigned short* __restrict__ WoT,
    const float* __restrict__ bo,
    const unsigned short* __restrict__ zb,
    const float* __restrict__ ln1w, const float* __restrict__ ln1b,
    unsigned short* __restrict__ z1b) {
  __shared__ __align__(16) char smem[137728];
  unsigned short* aout = (unsigned short*)smem;            // [32][520] bf16
  float* Kt = (float*)(smem + 33280);                      // [8][64][45] f32
  float* P  = (float*)(smem + 125440);                     // [8][32][12] f32
  unsigned short* Bst = (unsigned short*)(smem + 33280);   // [2][16384] bf16
  float* part = (float*)(smem + 98816);                    // [32][8][2] f32
  float* lnp  = (float*)(smem + 100864);                   // [32][2] f32

  const int tid = threadIdx.x;
  const int w = tid >> 6, lane = tid & 63;
  const int bid = blockIdx.x;       // 256 = 4 batches x 64 chunks
  const int b = bid >> 6;
  const int i0 = (bid & 63) * 32;
  const int b2048 = b * 2048;
  const int h64 = w * 64;

  // ---- phase A ----
  float* KtH = Kt + w * (64 * 45);
#pragma unroll 8
  for (int r = 0; r < 41; ++r) {
    int jloc = i0 - 9 + r;
    int jc = jloc < 0 ? 0 : jloc;
    KtH[lane * 45 + r] = bf2f(qkv[(size_t)(b2048 + jc) * 1536 + 512 + h64 + lane]);
  }
  const int qe = lane & 31, dh = lane >> 5;
  us8 qreg[4];
  {
    const unsigned short* qp = qkv + (size_t)(b2048 + i0 + qe) * 1536 + h64 + dh * 32;
#pragma unroll
    for (int t = 0; t < 4; ++t) qreg[t] = *(const us8*)(qp + t * 8);
  }
  float s[10];
#pragma unroll
  for (int jj = 0; jj < 10; ++jj) s[jj] = 0.f;
#pragma unroll
  for (int t = 0; t < 4; ++t) {
#pragma unroll
    for (int e = 0; e < 8; ++e) {
      float qd = bf2f(qreg[t][e]);
      int d = dh * 32 + t * 8 + e;
#pragma unroll
      for (int jj = 0; jj < 10; ++jj)
        s[jj] = fmaf(qd, KtH[d * 45 + qe + jj], s[jj]);
    }
  }
#pragma unroll
  for (int jj = 0; jj < 10; ++jj) s[jj] += __shfl_xor(s[jj], 32);
  const int iG = i0 + qe;
#pragma unroll
  for (int jj = 0; jj < 10; ++jj)
    s[jj] = (iG - 9 + jj >= 0) ? s[jj] * 0.125f : -1e30f;
  float mx = s[9];
#pragma unroll
  for (int jj = 0; jj < 9; ++jj) mx = fmaxf(mx, s[jj]);
  float den = 0.f;
#pragma unroll
  for (int jj = 0; jj < 10; ++jj) {
    s[jj] = __expf(s[jj] - mx);
    den += s[jj];
  }
  float inv = 1.f / den;
  if (lane < 32) {
#pragma unroll
    for (int jj = 0; jj < 10; ++jj) P[(w * 32 + qe) * 12 + jj] = s[jj] * inv;
  }
  for (int q0 = 0; q0 < 32; q0 += 4) {
    float vv[13];
#pragma unroll
    for (int t = 0; t < 13; ++t) {
      int jloc = i0 + q0 - 9 + t;
      int jc = jloc < 0 ? 0 : jloc;
      vv[t] = bf2f(qkv[(size_t)(b2048 + jc) * 1536 + 1024 + h64 + lane]);
    }
#pragma unroll
    for (int qq = 0; qq < 4; ++qq) {
      const int qy = q0 + qq;
      const float* pp = &P[(w * 32 + qy) * 12];
      float o = 0.f;
#pragma unroll
      for (int jj = 0; jj < 10; ++jj) o = fmaf(pp[jj], vv[qq + jj], o);
      aout[qy * 520 + h64 + lane] = f2bf(o);
    }
  }
  __syncthreads();

  // ---- phase B: 32x512 GEMM vs WoT, K=512, BK=32 ----
  const int q4 = lane >> 4, l15 = lane & 15;
  auto STAGE = [&](int buf, int k0) {
#pragma unroll
    for (int t = 0; t < 4; ++t) {
      int sI = t * 512 + tid;
      int R = sI >> 3;
      int c = (sI & 7) ^ (R & 7);
      int rr = 2 * R + (c >> 2);
      int kl = (c & 3) << 3;
      const unsigned short* gb = WoT + (size_t)rr * 512 + k0 + kl;
      const int dst = buf * 16384 + (t * 512 + w * 64) * 8;
      __builtin_amdgcn_global_load_lds((GUI*)gb, (LUI*)(Bst + dst), 16, 0, 0);
    }
  };
  asm volatile("s_waitcnt vmcnt(0)" ::: "memory");
  STAGE(0, 0);
  f32x4 acc[2][4] = {};
  for (int kt = 0; kt < 16; ++kt) {
    const int cur = kt & 1;
    if (kt + 1 < 16) {
      STAGE(cur ^ 1, (kt + 1) * 32);
      asm volatile("s_waitcnt vmcnt(4)" ::: "memory");
    } else {
      asm volatile("s_waitcnt vmcnt(0)" ::: "memory");
    }
    __builtin_amdgcn_s_barrier();
    bf16x8 af[2], bfr[4];
#pragma unroll
    for (int m = 0; m < 2; ++m) {
      int row = m * 16 + l15;
      af[m] = __builtin_bit_cast(bf16x8, *(const us8*)(aout + row * 520 + kt * 32 + q4 * 8));
    }
#pragma unroll
    for (int n = 0; n < 4; ++n) {
      int rr = h64 + n * 16 + l15;
      int R = rr >> 1;
      int d = (((rr & 1) << 2) + q4) ^ (R & 7);
      bfr[n] = __builtin_bit_cast(bf16x8, *(const us8*)(Bst + cur * 16384 + R * 64 + d * 8));
    }
    asm volatile("s_waitcnt lgkmcnt(0)" ::: "memory");
    __builtin_amdgcn_sched_barrier(0);
    __builtin_amdgcn_s_setprio(1);
#pragma unroll
    for (int m = 0; m < 2; ++m)
#pragma unroll
      for (int n = 0; n < 4; ++n)
        acc[m][n] = __builtin_amdgcn_mfma_f32_16x16x32_bf16(af[m], bfr[n], acc[m][n], 0, 0, 0);
    __builtin_amdgcn_s_setprio(0);
    __builtin_amdgcn_s_barrier();
  }

  // ---- epilogue: +bo, +zb, LN across 512 cols, write z1b ----
  float x[2][4][4];
  float psum[8], pss[8];
#pragma unroll
  for (int m = 0; m < 8; ++m) { psum[m] = 0.f; pss[m] = 0.f; }
#pragma unroll
  for (int m = 0; m < 2; ++m) {
#pragma unroll
    for (int n = 0; n < 4; ++n) {
      int col = h64 + n * 16 + l15;
      float bv = bo[col];
#pragma unroll
      for (int r = 0; r < 4; ++r) {
        int row = m * 16 + (q4 << 2) + r;
        float v = acc[m][n][r] + bv + bf2f(zb[(size_t)(b2048 + i0 + row) * 512 + col]);
        x[m][n][r] = v;
        psum[m * 4 + r] += v;
        pss[m * 4 + r] += v * v;
      }
    }
  }
#pragma unroll
  for (int m = 0; m < 8; ++m) {
#pragma unroll
    for (int o = 1; o < 16; o <<= 1) {
      psum[m] += __shfl_xor(psum[m], o);
      pss[m]  += __shfl_xor(pss[m], o);
    }
  }
  if (l15 == 0) {
#pragma unroll
    for (int m = 0; m < 2; ++m)
#pragma unroll
      for (int r = 0; r < 4; ++r) {
        int row = m * 16 + (q4 << 2) + r;
        part[(row * 8 + w) * 2 + 0] = psum[m * 4 + r];
        part[(row * 8 + w) * 2 + 1] = pss[m * 4 + r];
      }
  }
  __syncthreads();
  if (w == 0 && lane < 32) {
    float su = 0.f, ssq = 0.f;
#pragma unroll
    for (int p = 0; p < 8; ++p) {
      su  += part[(lane * 8 + p) * 2 + 0];
      ssq += part[(lane * 8 + p) * 2 + 1];
    }
    float mu = su * (1.f / 512.f);
    float var = ssq * (1.f / 512.f) - mu * mu;
    lnp[lane * 2 + 0] = mu;
    lnp[lane * 2 + 1] = rsqrtf(var + 1e-5f);
  }
  __syncthreads();
#pragma unroll
  for (int m = 0; m < 2; ++m) {
#pragma unroll
    for (int n = 0; n < 4; ++n) {
      int col = h64 + n * 16 + l15;
      float wv = ln1w[col], bbv = ln1b[col];
#pragma unroll
      for (int r = 0; r < 4; ++r) {
        int row = m * 16 + (q4 << 2) + r;
        float o = (x[m][n][r] - lnp[row * 2]) * lnp[row * 2 + 1] * wv + bbv;
        z1b[(size_t)(b2048 + i0 + row) * 512 + col] = f2bf(o);
      }
    }
  }
}

// ---------------- residual + LayerNorm (single addend) ------------
__global__ __launch_bounds__(256) void k_ln_out(const unsigned short* __restrict__ res,
                                                const unsigned short* __restrict__ add,
                                                const float* __restrict__ w,
                                                const float* __restrict__ bb,
                                                float* __restrict__ outp) {
  const int wave = threadIdx.x >> 6, lane = threadIdx.x & 63;
  const int row = blockIdx.x * 4 + wave;
  float x[8];
  us8 r = *(const us8*)(res + (size_t)row * 512 + lane * 8);
  us8 a = *(const us8*)(add + (size_t)row * 512 + lane * 8);
  float sum = 0.f, ss = 0.f;
#pragma unroll
  for (int j = 0; j < 8; ++j) {
    x[j] = bf2f(r[j]) + bf2f(a[j]);
    sum += x[j];
    ss += x[j] * x[j];
  }
#pragma unroll
  for (int m = 32; m >= 1; m >>= 1) {
    sum += __shfl_xor(sum, m);
    ss += __shfl_xor(ss, m);
  }
  const float mu = sum * (1.f / 512.f);
  float var = ss * (1.f / 512.f) - mu * mu;
  const float rstd = rsqrtf(var + 1e-5f);
  const int c = lane * 8;
  float4 u0, u1;
  float o[8];
#pragma unroll
  for (int j = 0; j < 8; ++j) o[j] = (x[j] - mu) * rstd * w[c + j] + bb[c + j];
  u0.x = o[0]; u0.y = o[1]; u0.z = o[2]; u0.w = o[3];
  u1.x = o[4]; u1.y = o[5]; u1.z = o[6]; u1.w = o[7];
  float4* o4 = (float4*)(outp + (size_t)row * 512 + c);
  o4[0] = u0; o4[1] = u1;
}

extern "C" void kernel_launch(void* const* d_in, const int* in_sizes, int n_in,
                              void* d_out, int out_size, void* d_ws, size_t ws_size,
                              hipStream_t stream) {
  const float* z    = (const float*)d_in[0];
  const float* Wq   = (const float*)d_in[1];
  const float* bq   = (const float*)d_in[2];
  const float* Wk   = (const float*)d_in[3];
  const float* bk   = (const float*)d_in[4];
  const float* Wv   = (const float*)d_in[5];
  const float* bv   = (const float*)d_in[6];
  const float* Wo   = (const float*)d_in[7];
  const float* bo   = (const float*)d_in[8];
  const float* ln1w = (const float*)d_in[9];
  const float* ln1b = (const float*)d_in[10];
  const float* W1   = (const float*)d_in[11];
  const float* b1   = (const float*)d_in[12];
  const float* W2   = (const float*)d_in[13];
  const float* b2   = (const float*)d_in[14];
  const float* ln2w = (const float*)d_in[15];
  const float* ln2b = (const float*)d_in[16];
  float* out = (float*)d_out;

  char* ws = (char*)d_ws;
  size_t off = 0;
  auto alloc = [&](size_t bytes) {
    char* p = ws + off;
    off += (bytes + 255) & ~(size_t)255;
    return p;
  };
  unsigned short* Wsq   = (unsigned short*)alloc((size_t)2048 * 512 * 2);  // WqT|WkT|WvT|WoT
  unsigned short* WTqkv = Wsq;
  unsigned short* WoT   = Wsq + (size_t)1536 * 512;
  unsigned short* W1T   = (unsigned short*)alloc((size_t)2048 * 512 * 2);
  unsigned short* W2T   = (unsigned short*)alloc((size_t)512 * 2048 * 2);
  float*          biasqkv = (float*)alloc(1536 * 4);
  unsigned short* zb    = (unsigned short*)alloc((size_t)8192 * 512 * 2);
  unsigned short* z1b   = (unsigned short*)alloc((size_t)8192 * 512 * 2);
  unsigned short* qkvb  = (unsigned short*)alloc((size_t)8192 * 1536 * 2);
  unsigned short* f2out = (unsigned short*)alloc((size_t)8192 * 512 * 2);
  unsigned short* ff    = qkvb;  // reuse qkvb (dead after k_awl)

  // fused prep dispatch
  k_prep<<<7169, 256, 0, stream>>>(z, zb, Wq, Wk, Wv, Wo, Wsq, W1, W1T, W2, W2T,
                                   bq, bk, bv, biasqkv);
  // QKV: [8192,512] @ [512,1536] -> qkvb, 256^2 tiles, 192 blocks
  k_qkv<<<dim3(6, 32), 512, 0, stream>>>(zb, WTqkv, biasqkv, qkvb, 512, 1536);
  // fused attention + Wo + LN1 -> z1b  (256 blocks, 32 rows each)
  k_awl<<<256, 512, 0, stream>>>(qkvb, WoT, bo, zb, ln1w, ln1b, z1b);
  // FFN1: [8192,512] @ [512,2048] + fast exact GELU -> ff, 256 blocks
  k_ffn1<<<dim3(8, 32), 512, 0, stream>>>(z1b, W1T, b1, ff, 512, 2048);
  // FFN2: [8192,2048] @ [2048,512] -> f2out, 128^2 tiles, 256 blocks (2/CU), no split-K
  k_ffn2<<<dim3(4, 64), 256, 0, stream>>>(ff, W2T, b2, f2out, 2048, 512);
  // out = LN(z1b + f2out)  (f32)
  k_ln_out<<<2048, 256, 0, stream>>>(z1b, f2out, ln2w, ln2b, out);
}

// Round 18
// 125.110 us; speedup vs baseline: 1.0673x; 1.0673x over previous
//
#include <hip/hip_runtime.h>
#include <cstdint>
#include <cstddef>

#define DEV __device__ __forceinline__

typedef __bf16 bf16x8 __attribute__((ext_vector_type(8)));
typedef float f32x4 __attribute__((ext_vector_type(4)));
typedef unsigned short us8 __attribute__((ext_vector_type(8)));
typedef unsigned short us4 __attribute__((ext_vector_type(4)));

typedef const __attribute__((address_space(1))) unsigned int GUI;
typedef __attribute__((address_space(3))) unsigned int LUI;

DEV unsigned short f2bf(float f) {
  unsigned int u = __builtin_bit_cast(unsigned int, f);
  u += 0x7fffu + ((u >> 16) & 1u);
  return (unsigned short)(u >> 16);
}
DEV float bf2f(unsigned short h) {
  unsigned int u = ((unsigned int)h) << 16;
  return __builtin_bit_cast(float, u);
}

// exact-GELU via A&S 7.1.26 erf approximation (|erf err| <= 1.5e-7)
DEV float gelu_exact(float x) {
  float xs = x * 0.70710678118654752f;
  float a = fabsf(xs);
  float t = __builtin_amdgcn_rcpf(fmaf(0.3275911f, a, 1.0f));
  float poly = t * fmaf(t, fmaf(t, fmaf(t, fmaf(t, 1.061405429f, -1.453152027f),
                                        1.421413741f), -0.284496736f), 0.254829592f);
  float erfa = 1.0f - poly * __expf(-a * a);
  float er = (xs < 0.f) ? -erfa : erfa;
  return 0.5f * x * (1.0f + er);
}

// ---------- fused prep: z->bf16, weight transposes, bias concat ----------
DEV void tr32(const float* __restrict__ in, unsigned short* __restrict__ out,
              int K, int N, int k0, int n0) {
  __shared__ float tile[32][33];
  const int tx = threadIdx.x & 31, ty = threadIdx.x >> 5;  // 256 thr = 32x8
#pragma unroll
  for (int i = 0; i < 32; i += 8)
    tile[ty + i][tx] = in[(size_t)(k0 + ty + i) * N + n0 + tx];
  __syncthreads();
#pragma unroll
  for (int i = 0; i < 32; i += 8)
    out[(size_t)(n0 + ty + i) * K + k0 + tx] = f2bf(tile[tx][ty + i]);
}

__global__ __launch_bounds__(256) void k_prep(
    const float* __restrict__ z, unsigned short* __restrict__ zb,
    const float* __restrict__ Wq, const float* __restrict__ Wk,
    const float* __restrict__ Wv, const float* __restrict__ Wo,
    unsigned short* __restrict__ Wsq,
    const float* __restrict__ W1, unsigned short* __restrict__ W1T,
    const float* __restrict__ W2, unsigned short* __restrict__ W2T,
    const float* __restrict__ bq, const float* __restrict__ bk,
    const float* __restrict__ bv, float* __restrict__ biasqkv) {
  const int j = blockIdx.x;
  const int tid = threadIdx.x;
  if (j < 4096) {
    int i = j * 256 + tid;
    float4 v = ((const float4*)z)[i];
    us4 o;
    o.x = f2bf(v.x); o.y = f2bf(v.y); o.z = f2bf(v.z); o.w = f2bf(v.w);
    *(us4*)(zb + (size_t)i * 4) = o;
  } else if (j < 5120) {
    int t = j - 4096;
    int mat = t >> 8, tile = t & 255;
    const float* in = mat == 0 ? Wq : mat == 1 ? Wk : mat == 2 ? Wv : Wo;
    tr32(in, Wsq + (size_t)mat * 262144, 512, 512, (tile >> 4) * 32, (tile & 15) * 32);
  } else if (j < 6144) {
    int t = j - 5120;
    tr32(W1, W1T, 512, 2048, (t / 64) * 32, (t % 64) * 32);
  } else if (j < 7168) {
    int t = j - 6144;
    tr32(W2, W2T, 2048, 512, (t / 16) * 32, (t % 16) * 32);
  } else {
    for (int i = tid; i < 1536; i += 256)
      biasqkv[i] = (i < 512) ? bq[i] : (i < 1024 ? bk[i - 512] : bv[i - 1024]);
  }
}

// ========== GEMM body: 256x256 tile, BK=64, 8 waves (round-8 best) ======
template <int MODE, int SPLITK>
DEV void gemm256_body(const unsigned short* __restrict__ A,
                      const unsigned short* __restrict__ BT,
                      const float* __restrict__ bias,
                      unsigned short* __restrict__ outp,
                      int K, int N) {
  __shared__ __align__(16) unsigned short As[2 * 16384];
  __shared__ __align__(16) unsigned short Bs[2 * 16384];
  const int tid = threadIdx.x;
  const int wave = tid >> 6, lane = tid & 63;
  const int wm = wave >> 2, wn = wave & 3;

  const int nx = gridDim.x, ny = gridDim.y;
  const int nwg = nx * ny * SPLITK;
  const int lid = (blockIdx.z * ny + blockIdx.y) * nx + blockIdx.x;
  const int q8 = nwg >> 3, r8 = nwg & 7;
  const int xcd = lid & 7, slot = lid >> 3;
  const int wid = (xcd < r8 ? xcd * (q8 + 1) : r8 * (q8 + 1) + (xcd - r8) * q8) + slot;
  const int nbz = nx * SPLITK;
  const int bxz = wid % nbz;
  const int by  = wid / nbz;
  const int bx  = bxz % nx;
  const int z   = bxz / nx;

  const int rbase = by * 256;
  const int nbase = bx * 256;
  const int nkt = (K / SPLITK) >> 6;
  const int kb = z * (K / SPLITK);

  float bv_[4];
#pragma unroll
  for (int n = 0; n < 4; ++n) {
    int gcol = nbase + wn * 64 + n * 16 + (lane & 15);
    bv_[n] = (z == 0) ? bias[gcol] : 0.f;
  }
  asm volatile("s_waitcnt vmcnt(0)" ::: "memory");

  auto STAGE = [&](int buf, int k0) {
#pragma unroll
    for (int t = 0; t < 4; ++t) {
      int s = t * 512 + tid;
      int row = s >> 3;
      int col = ((s & 7) ^ (row & 7)) << 3;
      const unsigned short* ga = A + (size_t)(rbase + row) * K + k0 + col;
      const unsigned short* gb = BT + (size_t)(nbase + row) * K + k0 + col;
      const int dst = buf * 16384 + (t * 512 + wave * 64) * 8;
      __builtin_amdgcn_global_load_lds((GUI*)ga, (LUI*)(As + dst), 16, 0, 0);
      __builtin_amdgcn_global_load_lds((GUI*)gb, (LUI*)(Bs + dst), 16, 0, 0);
    }
  };

  f32x4 acc[8][4] = {};
  STAGE(0, kb);

  for (int kt = 0; kt < nkt; ++kt) {
    const int cur = kt & 1;
    if (kt + 1 < nkt) {
      STAGE(cur ^ 1, kb + (kt + 1) * 64);
      asm volatile("s_waitcnt vmcnt(8)" ::: "memory");
    } else {
      asm volatile("s_waitcnt vmcnt(0)" ::: "memory");
    }
    __builtin_amdgcn_s_barrier();

#pragma unroll
    for (int ks = 0; ks < 2; ++ks) {
      bf16x8 af[8], bfr[4];
#pragma unroll
      for (int m = 0; m < 8; ++m) {
        int row = wm * 128 + m * 16 + (lane & 15);
        int ch = (ks * 4 + (lane >> 4)) ^ (row & 7);
        af[m] = __builtin_bit_cast(bf16x8, *(const us8*)(As + cur * 16384 + row * 64 + ch * 8));
      }
#pragma unroll
      for (int n = 0; n < 4; ++n) {
        int row = wn * 64 + n * 16 + (lane & 15);
        int ch = (ks * 4 + (lane >> 4)) ^ (row & 7);
        bfr[n] = __builtin_bit_cast(bf16x8, *(const us8*)(Bs + cur * 16384 + row * 64 + ch * 8));
      }
      __builtin_amdgcn_s_setprio(1);
#pragma unroll
      for (int m = 0; m < 8; ++m)
#pragma unroll
        for (int n = 0; n < 4; ++n)
          acc[m][n] = __builtin_amdgcn_mfma_f32_16x16x32_bf16(af[m], bfr[n], acc[m][n], 0, 0, 0);
      __builtin_amdgcn_s_setprio(0);
    }
    asm volatile("s_waitcnt lgkmcnt(0)" ::: "memory");
    __builtin_amdgcn_s_barrier();
  }

  unsigned short* opv = outp + (size_t)z * 8192 * N;
#pragma unroll
  for (int m = 0; m < 8; ++m) {
    int grow0 = rbase + wm * 128 + m * 16 + ((lane >> 4) << 2);
#pragma unroll
    for (int n = 0; n < 4; ++n) {
      int gcol = nbase + wn * 64 + n * 16 + (lane & 15);
#pragma unroll
      for (int r = 0; r < 4; ++r) {
        float v = acc[m][n][r] + bv_[n];
        if (MODE == 2) v = gelu_exact(v);
        opv[(size_t)(grow0 + r) * N + gcol] = f2bf(v);
      }
    }
  }
}

__global__ __launch_bounds__(512) void k_qkv(const unsigned short* __restrict__ A,
                                             const unsigned short* __restrict__ BT,
                                             const float* __restrict__ bias,
                                             unsigned short* __restrict__ outp, int K, int N) {
  gemm256_body<0, 1>(A, BT, bias, outp, K, N);
}
__global__ __launch_bounds__(512) void k_ffn1(const unsigned short* __restrict__ A,
                                              const unsigned short* __restrict__ BT,
                                              const float* __restrict__ bias,
                                              unsigned short* __restrict__ outp, int K, int N) {
  gemm256_body<2, 1>(A, BT, bias, outp, K, N);
}
__global__ __launch_bounds__(512) void k_ffn2(const unsigned short* __restrict__ A,
                                              const unsigned short* __restrict__ BT,
                                              const float* __restrict__ bias,
                                              unsigned short* __restrict__ outp, int K, int N) {
  gemm256_body<0, 4>(A, BT, bias, outp, K, N);
}

// ===== fused attention + Wo projection + LN1: z1b = LN(zb + attn@Wo + bo) =====
__global__ __launch_bounds__(512) void k_awl(
    const unsigned short* __restrict__ qkv,
    const unsigned short* __restrict__ WoT,
    const float* __restrict__ bo,
    const unsigned short* __restrict__ zb,
    const float* __restrict__ ln1w, const float* __restrict__ ln1b,
    unsigned short* __restrict__ z1b) {
  __shared__ __align__(16) char smem[137728];
  unsigned short* aout = (unsigned short*)smem;            // [32][520] bf16
  float* Kt = (float*)(smem + 33280);                      // [8][64][45] f32
  float* P  = (float*)(smem + 125440);                     // [8][32][12] f32
  unsigned short* Bst = (unsigned short*)(smem + 33280);   // [2][16384] bf16
  float* part = (float*)(smem + 98816);                    // [32][8][2] f32
  float* lnp  = (float*)(smem + 100864);                   // [32][2] f32

  const int tid = threadIdx.x;
  const int w = tid >> 6, lane = tid & 63;
  const int bid = blockIdx.x;       // 256 = 4 batches x 64 chunks
  const int b = bid >> 6;
  const int i0 = (bid & 63) * 32;
  const int b2048 = b * 2048;
  const int h64 = w * 64;

  // ---- phase A ----
  float* KtH = Kt + w * (64 * 45);
#pragma unroll 8
  for (int r = 0; r < 41; ++r) {
    int jloc = i0 - 9 + r;
    int jc = jloc < 0 ? 0 : jloc;
    KtH[lane * 45 + r] = bf2f(qkv[(size_t)(b2048 + jc) * 1536 + 512 + h64 + lane]);
  }
  const int qe = lane & 31, dh = lane >> 5;
  us8 qreg[4];
  {
    const unsigned short* qp = qkv + (size_t)(b2048 + i0 + qe) * 1536 + h64 + dh * 32;
#pragma unroll
    for (int t = 0; t < 4; ++t) qreg[t] = *(const us8*)(qp + t * 8);
  }
  float s[10];
#pragma unroll
  for (int jj = 0; jj < 10; ++jj) s[jj] = 0.f;
#pragma unroll
  for (int t = 0; t < 4; ++t) {
#pragma unroll
    for (int e = 0; e < 8; ++e) {
      float qd = bf2f(qreg[t][e]);
      int d = dh * 32 + t * 8 + e;
#pragma unroll
      for (int jj = 0; jj < 10; ++jj)
        s[jj] = fmaf(qd, KtH[d * 45 + qe + jj], s[jj]);
    }
  }
#pragma unroll
  for (int jj = 0; jj < 10; ++jj) s[jj] += __shfl_xor(s[jj], 32);
  const int iG = i0 + qe;
#pragma unroll
  for (int jj = 0; jj < 10; ++jj)
    s[jj] = (iG - 9 + jj >= 0) ? s[jj] * 0.125f : -1e30f;
  float mx = s[9];
#pragma unroll
  for (int jj = 0; jj < 9; ++jj) mx = fmaxf(mx, s[jj]);
  float den = 0.f;
#pragma unroll
  for (int jj = 0; jj < 10; ++jj) {
    s[jj] = __expf(s[jj] - mx);
    den += s[jj];
  }
  float inv = 1.f / den;
  if (lane < 32) {
#pragma unroll
    for (int jj = 0; jj < 10; ++jj) P[(w * 32 + qe) * 12 + jj] = s[jj] * inv;
  }
  for (int q0 = 0; q0 < 32; q0 += 4) {
    float vv[13];
#pragma unroll
    for (int t = 0; t < 13; ++t) {
      int jloc = i0 + q0 - 9 + t;
      int jc = jloc < 0 ? 0 : jloc;
      vv[t] = bf2f(qkv[(size_t)(b2048 + jc) * 1536 + 1024 + h64 + lane]);
    }
#pragma unroll
    for (int qq = 0; qq < 4; ++qq) {
      const int qy = q0 + qq;
      const float* pp = &P[(w * 32 + qy) * 12];
      float o = 0.f;
#pragma unroll
      for (int jj = 0; jj < 10; ++jj) o = fmaf(pp[jj], vv[qq + jj], o);
      aout[qy * 520 + h64 + lane] = f2bf(o);
    }
  }
  __syncthreads();

  // ---- phase B: 32x512 GEMM vs WoT, K=512, BK=32 ----
  const int q4 = lane >> 4, l15 = lane & 15;
  auto STAGE = [&](int buf, int k0) {
#pragma unroll
    for (int t = 0; t < 4; ++t) {
      int sI = t * 512 + tid;
      int R = sI >> 3;
      int c = (sI & 7) ^ (R & 7);
      int rr = 2 * R + (c >> 2);
      int kl = (c & 3) << 3;
      const unsigned short* gb = WoT + (size_t)rr * 512 + k0 + kl;
      const int dst = buf * 16384 + (t * 512 + w * 64) * 8;
      __builtin_amdgcn_global_load_lds((GUI*)gb, (LUI*)(Bst + dst), 16, 0, 0);
    }
  };
  asm volatile("s_waitcnt vmcnt(0)" ::: "memory");
  STAGE(0, 0);
  f32x4 acc[2][4] = {};
  for (int kt = 0; kt < 16; ++kt) {
    const int cur = kt & 1;
    if (kt + 1 < 16) {
      STAGE(cur ^ 1, (kt + 1) * 32);
      asm volatile("s_waitcnt vmcnt(4)" ::: "memory");
    } else {
      asm volatile("s_waitcnt vmcnt(0)" ::: "memory");
    }
    __builtin_amdgcn_s_barrier();
    bf16x8 af[2], bfr[4];
#pragma unroll
    for (int m = 0; m < 2; ++m) {
      int row = m * 16 + l15;
      af[m] = __builtin_bit_cast(bf16x8, *(const us8*)(aout + row * 520 + kt * 32 + q4 * 8));
    }
#pragma unroll
    for (int n = 0; n < 4; ++n) {
      int rr = h64 + n * 16 + l15;
      int R = rr >> 1;
      int d = (((rr & 1) << 2) + q4) ^ (R & 7);
      bfr[n] = __builtin_bit_cast(bf16x8, *(const us8*)(Bst + cur * 16384 + R * 64 + d * 8));
    }
    asm volatile("s_waitcnt lgkmcnt(0)" ::: "memory");
    __builtin_amdgcn_sched_barrier(0);
    __builtin_amdgcn_s_setprio(1);
#pragma unroll
    for (int m = 0; m < 2; ++m)
#pragma unroll
      for (int n = 0; n < 4; ++n)
        acc[m][n] = __builtin_amdgcn_mfma_f32_16x16x32_bf16(af[m], bfr[n], acc[m][n], 0, 0, 0);
    __builtin_amdgcn_s_setprio(0);
    __builtin_amdgcn_s_barrier();
  }

  // ---- epilogue: +bo, +zb, LN across 512 cols, write z1b ----
  float x[2][4][4];
  float psum[8], pss[8];
#pragma unroll
  for (int m = 0; m < 8; ++m) { psum[m] = 0.f; pss[m] = 0.f; }
#pragma unroll
  for (int m = 0; m < 2; ++m) {
#pragma unroll
    for (int n = 0; n < 4; ++n) {
      int col = h64 + n * 16 + l15;
      float bv = bo[col];
#pragma unroll
      for (int r = 0; r < 4; ++r) {
        int row = m * 16 + (q4 << 2) + r;
        float v = acc[m][n][r] + bv + bf2f(zb[(size_t)(b2048 + i0 + row) * 512 + col]);
        x[m][n][r] = v;
        psum[m * 4 + r] += v;
        pss[m * 4 + r] += v * v;
      }
    }
  }
#pragma unroll
  for (int m = 0; m < 8; ++m) {
#pragma unroll
    for (int o = 1; o < 16; o <<= 1) {
      psum[m] += __shfl_xor(psum[m], o);
      pss[m]  += __shfl_xor(pss[m], o);
    }
  }
  if (l15 == 0) {
#pragma unroll
    for (int m = 0; m < 2; ++m)
#pragma unroll
      for (int r = 0; r < 4; ++r) {
        int row = m * 16 + (q4 << 2) + r;
        part[(row * 8 + w) * 2 + 0] = psum[m * 4 + r];
        part[(row * 8 + w) * 2 + 1] = pss[m * 4 + r];
      }
  }
  __syncthreads();
  if (w == 0 && lane < 32) {
    float su = 0.f, ssq = 0.f;
#pragma unroll
    for (int p = 0; p < 8; ++p) {
      su  += part[(lane * 8 + p) * 2 + 0];
      ssq += part[(lane * 8 + p) * 2 + 1];
    }
    float mu = su * (1.f / 512.f);
    float var = ssq * (1.f / 512.f) - mu * mu;
    lnp[lane * 2 + 0] = mu;
    lnp[lane * 2 + 1] = rsqrtf(var + 1e-5f);
  }
  __syncthreads();
#pragma unroll
  for (int m = 0; m < 2; ++m) {
#pragma unroll
    for (int n = 0; n < 4; ++n) {
      int col = h64 + n * 16 + l15;
      float wv = ln1w[col], bbv = ln1b[col];
#pragma unroll
      for (int r = 0; r < 4; ++r) {
        int row = m * 16 + (q4 << 2) + r;
        float o = (x[m][n][r] - lnp[row * 2]) * lnp[row * 2 + 1] * wv + bbv;
        z1b[(size_t)(b2048 + i0 + row) * 512 + col] = f2bf(o);
      }
    }
  }
}

// ---------------- residual + LayerNorm (4 split-K planes) ---------
__global__ __launch_bounds__(256) void k_ln_out(const unsigned short* __restrict__ res,
                                                const unsigned short* __restrict__ add,
                                                const float* __restrict__ w,
                                                const float* __restrict__ bb,
                                                float* __restrict__ outp) {
  const size_t PLANE = (size_t)8192 * 512;
  const int wave = threadIdx.x >> 6, lane = threadIdx.x & 63;
  const int row = blockIdx.x * 4 + wave;
  float x[8];
  us8 r = *(const us8*)(res + (size_t)row * 512 + lane * 8);
#pragma unroll
  for (int j = 0; j < 8; ++j) x[j] = bf2f(r[j]);
#pragma unroll
  for (int p = 0; p < 4; ++p) {
    us8 a = *(const us8*)(add + p * PLANE + (size_t)row * 512 + lane * 8);
#pragma unroll
    for (int j = 0; j < 8; ++j) x[j] += bf2f(a[j]);
  }
  float sum = 0.f, ss = 0.f;
#pragma unroll
  for (int j = 0; j < 8; ++j) {
    sum += x[j];
    ss += x[j] * x[j];
  }
#pragma unroll
  for (int m = 32; m >= 1; m >>= 1) {
    sum += __shfl_xor(sum, m);
    ss += __shfl_xor(ss, m);
  }
  const float mu = sum * (1.f / 512.f);
  float var = ss * (1.f / 512.f) - mu * mu;
  const float rstd = rsqrtf(var + 1e-5f);
  const int c = lane * 8;
  float4 u0, u1;
  float o[8];
#pragma unroll
  for (int j = 0; j < 8; ++j) o[j] = (x[j] - mu) * rstd * w[c + j] + bb[c + j];
  u0.x = o[0]; u0.y = o[1]; u0.z = o[2]; u0.w = o[3];
  u1.x = o[4]; u1.y = o[5]; u1.z = o[6]; u1.w = o[7];
  float4* o4 = (float4*)(outp + (size_t)row * 512 + c);
  o4[0] = u0; o4[1] = u1;
}

extern "C" void kernel_launch(void* const* d_in, const int* in_sizes, int n_in,
                              void* d_out, int out_size, void* d_ws, size_t ws_size,
                              hipStream_t stream) {
  const float* z    = (const float*)d_in[0];
  const float* Wq   = (const float*)d_in[1];
  const float* bq   = (const float*)d_in[2];
  const float* Wk   = (const float*)d_in[3];
  const float* bk   = (const float*)d_in[4];
  const float* Wv   = (const float*)d_in[5];
  const float* bv   = (const float*)d_in[6];
  const float* Wo   = (const float*)d_in[7];
  const float* bo   = (const float*)d_in[8];
  const float* ln1w = (const float*)d_in[9];
  const float* ln1b = (const float*)d_in[10];
  const float* W1   = (const float*)d_in[11];
  const float* b1   = (const float*)d_in[12];
  const float* W2   = (const float*)d_in[13];
  const float* b2   = (const float*)d_in[14];
  const float* ln2w = (const float*)d_in[15];
  const float* ln2b = (const float*)d_in[16];
  float* out = (float*)d_out;

  char* ws = (char*)d_ws;
  size_t off = 0;
  auto alloc = [&](size_t bytes) {
    char* p = ws + off;
    off += (bytes + 255) & ~(size_t)255;
    return p;
  };
  unsigned short* Wsq   = (unsigned short*)alloc((size_t)2048 * 512 * 2);  // WqT|WkT|WvT|WoT
  unsigned short* WTqkv = Wsq;
  unsigned short* WoT   = Wsq + (size_t)1536 * 512;
  unsigned short* W1T   = (unsigned short*)alloc((size_t)2048 * 512 * 2);
  unsigned short* W2T   = (unsigned short*)alloc((size_t)512 * 2048 * 2);
  float*          biasqkv = (float*)alloc(1536 * 4);
  unsigned short* zb    = (unsigned short*)alloc((size_t)8192 * 512 * 2);
  unsigned short* z1b   = (unsigned short*)alloc((size_t)8192 * 512 * 2);
  unsigned short* qkvb  = (unsigned short*)alloc((size_t)8192 * 1536 * 2);
  unsigned short* p1    = (unsigned short*)alloc((size_t)4 * 8192 * 512 * 2);  // 4 split-K planes
  unsigned short* ff    = qkvb;  // reuse qkvb (dead after k_awl)

  // fused prep dispatch
  k_prep<<<7169, 256, 0, stream>>>(z, zb, Wq, Wk, Wv, Wo, Wsq, W1, W1T, W2, W2T,
                                   bq, bk, bv, biasqkv);
  // QKV: [8192,512] @ [512,1536] -> qkvb, 256^2 tiles, 192 blocks
  k_qkv<<<dim3(6, 32), 512, 0, stream>>>(zb, WTqkv, biasqkv, qkvb, 512, 1536);
  // fused attention + Wo + LN1 -> z1b  (256 blocks, 32 rows each)
  k_awl<<<256, 512, 0, stream>>>(qkvb, WoT, bo, zb, ln1w, ln1b, z1b);
  // FFN1: [8192,512] @ [512,2048] + fast exact GELU -> ff, 256 blocks
  k_ffn1<<<dim3(8, 32), 512, 0, stream>>>(z1b, W1T, b1, ff, 512, 2048);
  // FFN2: [8192,2048] @ [2048,512], split-K=4 -> p1[0..3], 256 blocks
  k_ffn2<<<dim3(2, 32, 4), 512, 0, stream>>>(ff, W2T, b2, p1, 2048, 512);
  // out = LN(z1b + p1[0..3])  (f32)
  k_ln_out<<<2048, 256, 0, stream>>>(z1b, p1, ln2w, ln2b, out);
}